// Round 3
// baseline (1176.896 us; speedup 1.0000x reference)
//
#include <hip/hip_runtime.h>

#define EDGES 400000
#define DIM 128

typedef __attribute__((ext_vector_type(8))) short bf16x8;
typedef __attribute__((ext_vector_type(4))) float f32x4;

// fp32 -> bf16 round-to-nearest-even
__device__ __forceinline__ short f2bf(float f) {
    unsigned u = __builtin_bit_cast(unsigned, f);
    unsigned r = (u + 0x7fffu + ((u >> 16) & 1u)) >> 16;
    return (short)r;
}

// Rearrange W1 [768][384] fp32 -> bf16 frag-major for 16x16x32 MFMA B-operand:
// frag (nt, s): lane holds B[k = (lane>>4)*8 + j][n = lane&15], k-step s, n-tile nt.
__global__ void prep_w1(const float* __restrict__ W1, short* __restrict__ W1f) {
    int idx = blockIdx.x * 256 + threadIdx.x;       // 294912 = 48*12*64*8
    int j    = idx & 7;
    int lane = (idx >> 3) & 63;
    int fs   = idx >> 9;                            // nt*12 + s
    int s    = fs % 12;
    int nt   = fs / 12;
    int n = nt * 16 + (lane & 15);
    int k = s * 32 + (lane >> 4) * 8 + j;
    W1f[idx] = f2bf(W1[n * 384 + k]);
}

// No-LDS design: B fragments are loaded straight from global (frag-major W1f,
// 576 KB -> L2/L1 resident) into a register ping-pong. Zero LDS traffic, zero
// barriers. 256 threads = 4 waves; each wave owns 2 M-tiles (32 edges); block
// covers 128 edges; grid = 3125 exactly. A (feat) in registers; h never
// materialized (bias+relu+W2 reduce in the per-chunk epilogue).
__global__ __launch_bounds__(256, 1)
void edge_mlp(const float* __restrict__ x,
              const int*   __restrict__ ei,      // [2][EDGES]
              const float* __restrict__ b1,      // [768]
              const float* __restrict__ W2,      // [768]
              const float* __restrict__ b2p,     // [1]
              const short* __restrict__ W1f,     // frag-major bf16 W1
              float* __restrict__ out)           // [EDGES]
{
    const int tid  = threadIdx.x;
    const int lane = tid & 63;
    const int wave = tid >> 6;                   // 0..3
    const int m    = lane & 15;
    const int quad = lane >> 4;
    const int eb   = blockIdx.x * 128;

    // ---- build A fragments in registers: 2 M-tiles x 12 K-steps (96 VGPR) ----
    // A-frag layout: lane holds A[m=lane&15][k=quad*8+j]; sections s 0-3 mean,
    // 4-7 prod, 8-11 sqdiff share the same x columns -> each x chunk loaded once.
    bf16x8 afrag[2][12];
    #pragma unroll
    for (int T = 0; T < 2; ++T) {
        int e = eb + wave * 32 + T * 16 + m;
        const float* r0 = x + (size_t)ei[e] * DIM;
        const float* r1 = x + (size_t)ei[EDGES + e] * DIM;
        #pragma unroll
        for (int i = 0; i < 4; ++i) {
            int c = i * 32 + quad * 8;
            float4 a0 = *(const float4*)(r0 + c);
            float4 a1 = *(const float4*)(r0 + c + 4);
            float4 c0 = *(const float4*)(r1 + c);
            float4 c1 = *(const float4*)(r1 + c + 4);
            float t0[8] = {a0.x,a0.y,a0.z,a0.w,a1.x,a1.y,a1.z,a1.w};
            float t1[8] = {c0.x,c0.y,c0.z,c0.w,c1.x,c1.y,c1.z,c1.w};
            bf16x8 fm, fp, fd;
            #pragma unroll
            for (int j = 0; j < 8; ++j) {
                float aa = t0[j], bb = t1[j];
                fm[j] = f2bf((aa + bb) * 0.5f);
                fp[j] = f2bf(aa * bb);
                float dd = aa - bb;
                fd[j] = f2bf(dd * dd);
            }
            afrag[T][i]     = fm;   // mean      -> k in [0,128)
            afrag[T][i + 4] = fp;   // product   -> k in [128,256)
            afrag[T][i + 8] = fd;   // sq. diff  -> k in [256,384)
        }
    }

    float yp0[4] = {0.f, 0.f, 0.f, 0.f};
    float yp1[4] = {0.f, 0.f, 0.f, 0.f};

    // B fragment pointer for this lane: frag (nt,s) at element (nt*12+s)*64+lane
    const bf16x8* __restrict__ bg = (const bf16x8*)W1f + lane;

    bf16x8 bufA[12], bufB[12];

    // preload chunks 0 and 1
    #pragma unroll
    for (int s = 0; s < 12; ++s) bufA[s] = bg[s * 64];
    #pragma unroll
    for (int s = 0; s < 12; ++s) bufB[s] = bg[768 + s * 64];

#define COMPUTE(buf, ntv)                                                     \
    {                                                                         \
        f32x4 acc0 = {0.f, 0.f, 0.f, 0.f};                                    \
        f32x4 acc1 = {0.f, 0.f, 0.f, 0.f};                                    \
        _Pragma("unroll")                                                     \
        for (int s = 0; s < 12; ++s) {                                        \
            acc0 = __builtin_amdgcn_mfma_f32_16x16x32_bf16(afrag[0][s], buf[s], acc0, 0, 0, 0); \
            acc1 = __builtin_amdgcn_mfma_f32_16x16x32_bf16(afrag[1][s], buf[s], acc1, 0, 0, 0); \
        }                                                                     \
        int ng = (ntv) * 16 + m;                                              \
        float bias = b1[ng];                                                  \
        float w2v  = W2[ng];                                                  \
        _Pragma("unroll")                                                     \
        for (int r = 0; r < 4; ++r) {                                         \
            yp0[r] = fmaf(fmaxf(acc0[r] + bias, 0.f), w2v, yp0[r]);           \
            yp1[r] = fmaf(fmaxf(acc1[r] + bias, 0.f), w2v, yp1[r]);           \
        }                                                                     \
    }

#define LOADB(buf, ntv)                                                       \
    {                                                                         \
        const bf16x8* __restrict__ bp = bg + (size_t)(ntv) * 768;             \
        _Pragma("unroll")                                                     \
        for (int s = 0; s < 12; ++s) buf[s] = bp[s * 64];                     \
    }

    for (int nt = 0; nt < 48; nt += 2) {
        // chunk nt from bufA; then refill bufA with chunk nt+2 (clamped dummy at end)
        COMPUTE(bufA, nt);
        { int nn = (nt + 2 < 48) ? nt + 2 : 46; LOADB(bufA, nn); }
        // chunk nt+1 from bufB; then refill bufB with chunk nt+3
        COMPUTE(bufB, nt + 1);
        { int nn = (nt + 3 < 48) ? nt + 3 : 47; LOADB(bufB, nn); }
    }
#undef COMPUTE
#undef LOADB

    // reduce over the 16 n-lanes (m nibble) of each quad-group
    #pragma unroll
    for (int off = 8; off >= 1; off >>= 1) {
        #pragma unroll
        for (int r = 0; r < 4; ++r) {
            yp0[r] += __shfl_xor(yp0[r], off, 64);
            yp1[r] += __shfl_xor(yp1[r], off, 64);
        }
    }
    if (m == 0) {
        float b2v = b2p[0];
        int e0 = eb + wave * 32 + quad * 4;
        #pragma unroll
        for (int r = 0; r < 4; ++r) {
            out[e0 + r]      = yp0[r] + b2v;
            out[e0 + 16 + r] = yp1[r] + b2v;
        }
    }
}

extern "C" void kernel_launch(void* const* d_in, const int* in_sizes, int n_in,
                              void* d_out, int out_size, void* d_ws, size_t ws_size,
                              hipStream_t stream) {
    const float* x  = (const float*)d_in[0];
    const int*   ei = (const int*)  d_in[1];
    const float* W1 = (const float*)d_in[5];
    const float* b1 = (const float*)d_in[6];
    const float* W2 = (const float*)d_in[7];
    const float* b2 = (const float*)d_in[8];
    short* W1f = (short*)d_ws;                 // 589824 B frag-major bf16 W1
    float* out = (float*)d_out;

    prep_w1<<<1152, 256, 0, stream>>>(W1, W1f);
    edge_mlp<<<3125, 256, 0, stream>>>(x, ei, b1, W2, b2, W1f, out);
}

// Round 4
// 543.066 us; speedup vs baseline: 2.1671x; 2.1671x over previous
//
#include <hip/hip_runtime.h>

#define EDGES 400000
#define DIM 128

typedef __attribute__((ext_vector_type(8))) short bf16x8;
typedef __attribute__((ext_vector_type(4))) float f32x4;

// fp32 -> bf16 round-to-nearest-even
__device__ __forceinline__ short f2bf(float f) {
    unsigned u = __builtin_bit_cast(unsigned, f);
    unsigned r = (u + 0x7fffu + ((u >> 16) & 1u)) >> 16;
    return (short)r;
}

// Rearrange W1 [768][384] fp32 -> bf16 frag-major for 16x16x32 MFMA B-operand:
// frag (nt, s): lane holds B[k = (lane>>4)*8 + j][n = lane&15], k-step s, n-tile nt.
__global__ void prep_w1(const float* __restrict__ W1, short* __restrict__ W1f) {
    int idx = blockIdx.x * 256 + threadIdx.x;       // 294912 = 48*12*64*8
    int j    = idx & 7;
    int lane = (idx >> 3) & 63;
    int fs   = idx >> 9;                            // nt*12 + s
    int s    = fs % 12;
    int nt   = fs / 12;
    int n = nt * 16 + (lane & 15);
    int k = s * 32 + (lane >> 4) * 8 + j;
    W1f[idx] = f2bf(W1[n * 384 + k]);
}

// R1 structure (async global_load_lds staging, double-buffered LDS — the only
// staging path the compiler can't spill or sink) but M per wave doubled to 64
// edges: afrag[4][12] = 192 VGPR, each B-fragment ds_read_b128 now feeds 4
// MFMAs. launch_bounds(128,1) -> 512-VGPR cap (R2's spill was the 256 cap).
// Block: 128 threads = 2 waves = 128 edges; grid 3125 exact. b1/W2 staged in
// LDS once per block so the chunk loop has zero global loads.
__global__ __launch_bounds__(128, 1)
void edge_mlp(const float* __restrict__ x,
              const int*   __restrict__ ei,      // [2][EDGES]
              const float* __restrict__ b1,      // [768]
              const float* __restrict__ W2,      // [768]
              const float* __restrict__ b2p,     // [1]
              const short* __restrict__ W1f,     // frag-major bf16 W1
              float* __restrict__ out)           // [EDGES]
{
    __shared__ short sB[2][12 * 512];            // 2 x 12 KB B double-buffer
    __shared__ float sBias[768];
    __shared__ float sW2[768];

    const int tid  = threadIdx.x;
    const int lane = tid & 63;
    const int wave = tid >> 6;                   // 0..1
    const int m    = lane & 15;
    const int quad = lane >> 4;
    const int eb   = blockIdx.x * 128;

    // ---- async stage N-chunk 0 (12 frags; each wave issues 6) ----
    #pragma unroll
    for (int jj = 0; jj < 6; ++jj) {
        int s = wave * 6 + jj;
        __builtin_amdgcn_global_load_lds(
            (const __attribute__((address_space(1))) void*)(W1f + (s << 9) + lane * 8),
            (__attribute__((address_space(3))) void*)(&sB[0][s << 9]),
            16, 0, 0);
    }

    // stage epilogue constants (once per block)
    #pragma unroll
    for (int i = tid; i < 768; i += 128) {
        sBias[i] = b1[i];
        sW2[i]   = W2[i];
    }

    // ---- build A fragments in registers: 4 M-tiles x 12 K-steps (192 VGPR) ----
    // A-frag layout: lane holds A[m=lane&15][k=quad*8+j]; sections s 0-3 mean,
    // 4-7 prod, 8-11 sqdiff share the same x columns -> each x chunk loaded once.
    bf16x8 afrag[4][12];
    #pragma unroll
    for (int T = 0; T < 4; ++T) {
        int e = eb + wave * 64 + T * 16 + m;
        const float* r0 = x + (size_t)ei[e] * DIM;
        const float* r1 = x + (size_t)ei[EDGES + e] * DIM;
        #pragma unroll
        for (int i = 0; i < 4; ++i) {
            int c = i * 32 + quad * 8;
            float4 a0 = *(const float4*)(r0 + c);
            float4 a1 = *(const float4*)(r0 + c + 4);
            float4 c0 = *(const float4*)(r1 + c);
            float4 c1 = *(const float4*)(r1 + c + 4);
            float t0[8] = {a0.x,a0.y,a0.z,a0.w,a1.x,a1.y,a1.z,a1.w};
            float t1[8] = {c0.x,c0.y,c0.z,c0.w,c1.x,c1.y,c1.z,c1.w};
            bf16x8 fm, fp, fd;
            #pragma unroll
            for (int j = 0; j < 8; ++j) {
                float aa = t0[j], bb = t1[j];
                fm[j] = f2bf((aa + bb) * 0.5f);
                fp[j] = f2bf(aa * bb);
                float dd = aa - bb;
                fd[j] = f2bf(dd * dd);
            }
            afrag[T][i]     = fm;   // mean      -> k in [0,128)
            afrag[T][i + 4] = fp;   // product   -> k in [128,256)
            afrag[T][i + 8] = fd;   // sq. diff  -> k in [256,384)
        }
    }

    float yp[4][4];
    #pragma unroll
    for (int t = 0; t < 4; ++t)
        #pragma unroll
        for (int r = 0; r < 4; ++r) yp[t][r] = 0.f;

    __syncthreads();   // chunk 0 staged (vmcnt drain + barrier)

    for (int nt = 0; nt < 48; ++nt) {
        const int cur = nt & 1;

        // prefetch next chunk into the other buffer; the 48-MFMA body below
        // gives it ~900 cyc of cover before the end-of-iter barrier drain
        if (nt + 1 < 48) {
            const short* src = W1f + (size_t)(nt + 1) * 6144;
            #pragma unroll
            for (int jj = 0; jj < 6; ++jj) {
                int s = wave * 6 + jj;
                __builtin_amdgcn_global_load_lds(
                    (const __attribute__((address_space(1))) void*)(src + (s << 9) + lane * 8),
                    (__attribute__((address_space(3))) void*)(&sB[cur ^ 1][s << 9]),
                    16, 0, 0);
            }
        }

        f32x4 acc[4];
        #pragma unroll
        for (int t = 0; t < 4; ++t) acc[t] = (f32x4){0.f, 0.f, 0.f, 0.f};

        const bf16x8* bp = (const bf16x8*)sB[cur];
        #pragma unroll
        for (int s = 0; s < 12; ++s) {
            bf16x8 bfrag = bp[(s << 6) + lane];   // conflict-free contiguous 1 KB
            #pragma unroll
            for (int t = 0; t < 4; ++t)
                acc[t] = __builtin_amdgcn_mfma_f32_16x16x32_bf16(afrag[t][s], bfrag, acc[t], 0, 0, 0);
        }

        // epilogue: D layout — edge-within-tile = quad*4+r, n-within-chunk = lane&15
        int ng = nt * 16 + m;
        float bias = sBias[ng];   // 16 consecutive words, quad-broadcast: conflict-free
        float w2v  = sW2[ng];
        #pragma unroll
        for (int t = 0; t < 4; ++t)
            #pragma unroll
            for (int r = 0; r < 4; ++r)
                yp[t][r] = fmaf(fmaxf(acc[t][r] + bias, 0.f), w2v, yp[t][r]);

        __syncthreads();
    }

    // reduce over the 16 n-lanes (m nibble) of each quad-group
    #pragma unroll
    for (int off = 8; off >= 1; off >>= 1)
        #pragma unroll
        for (int t = 0; t < 4; ++t)
            #pragma unroll
            for (int r = 0; r < 4; ++r)
                yp[t][r] += __shfl_xor(yp[t][r], off, 64);

    if (m == 0) {
        float b2v = b2p[0];
        #pragma unroll
        for (int t = 0; t < 4; ++t) {
            int e0 = eb + wave * 64 + t * 16 + quad * 4;
            #pragma unroll
            for (int r = 0; r < 4; ++r)
                out[e0 + r] = yp[t][r] + b2v;
        }
    }
}

extern "C" void kernel_launch(void* const* d_in, const int* in_sizes, int n_in,
                              void* d_out, int out_size, void* d_ws, size_t ws_size,
                              hipStream_t stream) {
    const float* x  = (const float*)d_in[0];
    const int*   ei = (const int*)  d_in[1];
    const float* W1 = (const float*)d_in[5];
    const float* b1 = (const float*)d_in[6];
    const float* W2 = (const float*)d_in[7];
    const float* b2 = (const float*)d_in[8];
    short* W1f = (short*)d_ws;                 // 589824 B frag-major bf16 W1
    float* out = (float*)d_out;

    prep_w1<<<1152, 256, 0, stream>>>(W1, W1f);
    edge_mlp<<<3125, 128, 0, stream>>>(x, ei, b1, W2, b2, W1f, out);
}

// Round 5
// 467.488 us; speedup vs baseline: 2.5175x; 1.1617x over previous
//
#include <hip/hip_runtime.h>

#define EDGES 400000
#define DIM 128

typedef __attribute__((ext_vector_type(8))) short bf16x8;
typedef __attribute__((ext_vector_type(4))) float f32x4;

// fp32 -> bf16 round-to-nearest-even
__device__ __forceinline__ short f2bf(float f) {
    unsigned u = __builtin_bit_cast(unsigned, f);
    unsigned r = (u + 0x7fffu + ((u >> 16) & 1u)) >> 16;
    return (short)r;
}

// Rearrange W1 [768][384] fp32 -> bf16 frag-major for 16x16x32 MFMA B-operand:
// frag (nt, s): lane holds B[k = (lane>>4)*8 + j][n = lane&15], k-step s, n-tile nt.
__global__ void prep_w1(const float* __restrict__ W1, short* __restrict__ W1f) {
    int idx = blockIdx.x * 256 + threadIdx.x;       // 294912 = 48*12*64*8
    int j    = idx & 7;
    int lane = (idx >> 3) & 63;
    int fs   = idx >> 9;                            // nt*12 + s
    int s    = fs % 12;
    int nt   = fs / 12;
    int n = nt * 16 + (lane & 15);
    int k = s * 32 + (lane >> 4) * 8 + j;
    W1f[idx] = f2bf(W1[n * 384 + k]);
}

// M_w=48: 3 M-tiles/wave (afrag = 144 VGPR, peak liveness ~230 — fits the 256
// VGPR arch budget that R2/R4 proved is the real cap). Each B-fragment
// ds_read_b128 feeds 3 MFMAs; LDS traffic 6 GB vs R1's 9 GB. Chunks staged in
// PAIRS (24 KB per buffer) -> 24 barrier iterations, not 48. 256 threads =
// 4 waves = 192 edges/block; grid 2084 (tail clamped/guarded). b1/W2 in LDS.
__global__ __launch_bounds__(256, 2)
void edge_mlp(const float* __restrict__ x,
              const int*   __restrict__ ei,      // [2][EDGES]
              const float* __restrict__ b1,      // [768]
              const float* __restrict__ W2,      // [768]
              const float* __restrict__ b2p,     // [1]
              const short* __restrict__ W1f,     // frag-major bf16 W1
              float* __restrict__ out)           // [EDGES]
{
    __shared__ short sB[2][24 * 512];            // 2 x 24 KB: chunk-PAIR buffers
    __shared__ float sBias[768];
    __shared__ float sW2[768];

    const int tid  = threadIdx.x;
    const int lane = tid & 63;
    const int wave = tid >> 6;                   // 0..3
    const int m    = lane & 15;
    const int quad = lane >> 4;
    const int eb   = blockIdx.x * 192;

    // ---- async stage chunk-pair 0 (24 frags; each wave issues 6) ----
    #pragma unroll
    for (int jj = 0; jj < 6; ++jj) {
        int f = wave * 6 + jj;                   // frag 0..23
        __builtin_amdgcn_global_load_lds(
            (const __attribute__((address_space(1))) void*)(W1f + (f << 9) + lane * 8),
            (__attribute__((address_space(3))) void*)(&sB[0][f << 9]),
            16, 0, 0);
    }

    // stage epilogue constants (once per block)
    for (int i = tid; i < 768; i += 256) {
        sBias[i] = b1[i];
        sW2[i]   = W2[i];
    }

    // ---- build A fragments: 3 M-tiles x 12 K-steps (144 VGPR) ----
    // lane holds A[m=lane&15][k=quad*8+j]; sections s 0-3 mean, 4-7 prod,
    // 8-11 sqdiff share the same x columns -> each x chunk loaded once.
    bf16x8 afrag[3][12];
    #pragma unroll
    for (int T = 0; T < 3; ++T) {
        int e = eb + wave * 48 + T * 16 + m;
        int ec = e < EDGES ? e : EDGES - 1;      // tail clamp (results discarded)
        const float* r0 = x + (size_t)ei[ec] * DIM;
        const float* r1 = x + (size_t)ei[EDGES + ec] * DIM;
        #pragma unroll
        for (int i = 0; i < 4; ++i) {
            int c = i * 32 + quad * 8;
            float4 a0 = *(const float4*)(r0 + c);
            float4 a1 = *(const float4*)(r0 + c + 4);
            float4 c0 = *(const float4*)(r1 + c);
            float4 c1 = *(const float4*)(r1 + c + 4);
            float t0[8] = {a0.x,a0.y,a0.z,a0.w,a1.x,a1.y,a1.z,a1.w};
            float t1[8] = {c0.x,c0.y,c0.z,c0.w,c1.x,c1.y,c1.z,c1.w};
            bf16x8 fm, fp, fd;
            #pragma unroll
            for (int j = 0; j < 8; ++j) {
                float aa = t0[j], bb = t1[j];
                fm[j] = f2bf((aa + bb) * 0.5f);
                fp[j] = f2bf(aa * bb);
                float dd = aa - bb;
                fd[j] = f2bf(dd * dd);
            }
            afrag[T][i]     = fm;   // mean      -> k in [0,128)
            afrag[T][i + 4] = fp;   // product   -> k in [128,256)
            afrag[T][i + 8] = fd;   // sq. diff  -> k in [256,384)
        }
    }

    float yp[3][4];
    #pragma unroll
    for (int t = 0; t < 3; ++t)
        #pragma unroll
        for (int r = 0; r < 4; ++r) yp[t][r] = 0.f;

    __syncthreads();   // pair 0 staged (vmcnt drain + barrier)

    for (int p = 0; p < 24; ++p) {
        const int cur = p & 1;

        // prefetch next chunk-pair; ~96 MFMAs of cover before the barrier
        if (p + 1 < 24) {
            const short* src = W1f + (size_t)(p + 1) * 12288;
            #pragma unroll
            for (int jj = 0; jj < 6; ++jj) {
                int f = wave * 6 + jj;
                __builtin_amdgcn_global_load_lds(
                    (const __attribute__((address_space(1))) void*)(src + (f << 9) + lane * 8),
                    (__attribute__((address_space(3))) void*)(&sB[cur ^ 1][f << 9]),
                    16, 0, 0);
            }
        }

        #pragma unroll
        for (int c = 0; c < 2; ++c) {            // the two chunks of the pair
            f32x4 acc[3];
            #pragma unroll
            for (int t = 0; t < 3; ++t) acc[t] = (f32x4){0.f, 0.f, 0.f, 0.f};

            const bf16x8* bp = (const bf16x8*)&sB[cur][c * 6144];
            #pragma unroll
            for (int s = 0; s < 12; ++s) {
                bf16x8 bfrag = bp[(s << 6) + lane];   // conflict-free 1 KB frag
                #pragma unroll
                for (int t = 0; t < 3; ++t)
                    acc[t] = __builtin_amdgcn_mfma_f32_16x16x32_bf16(afrag[t][s], bfrag, acc[t], 0, 0, 0);
            }

            // epilogue: D layout — edge-within-tile = quad*4+r, n = lane&15
            int ng = (p * 2 + c) * 16 + m;
            float bias = sBias[ng];
            float w2v  = sW2[ng];
            #pragma unroll
            for (int t = 0; t < 3; ++t)
                #pragma unroll
                for (int r = 0; r < 4; ++r)
                    yp[t][r] = fmaf(fmaxf(acc[t][r] + bias, 0.f), w2v, yp[t][r]);
        }

        __syncthreads();
    }

    // reduce over the 16 n-lanes (m nibble) of each quad-group
    #pragma unroll
    for (int off = 8; off >= 1; off >>= 1)
        #pragma unroll
        for (int t = 0; t < 3; ++t)
            #pragma unroll
            for (int r = 0; r < 4; ++r)
                yp[t][r] += __shfl_xor(yp[t][r], off, 64);

    if (m == 0) {
        float b2v = b2p[0];
        #pragma unroll
        for (int t = 0; t < 3; ++t) {
            int e0 = eb + wave * 48 + t * 16 + quad * 4;
            #pragma unroll
            for (int r = 0; r < 4; ++r)
                if (e0 + r < EDGES) out[e0 + r] = yp[t][r] + b2v;
        }
    }
}

extern "C" void kernel_launch(void* const* d_in, const int* in_sizes, int n_in,
                              void* d_out, int out_size, void* d_ws, size_t ws_size,
                              hipStream_t stream) {
    const float* x  = (const float*)d_in[0];
    const int*   ei = (const int*)  d_in[1];
    const float* W1 = (const float*)d_in[5];
    const float* b1 = (const float*)d_in[6];
    const float* W2 = (const float*)d_in[7];
    const float* b2 = (const float*)d_in[8];
    short* W1f = (short*)d_ws;                 // 589824 B frag-major bf16 W1
    float* out = (float*)d_out;

    prep_w1<<<1152, 256, 0, stream>>>(W1, W1f);
    edge_mlp<<<2084, 256, 0, stream>>>(x, ei, b1, W2, b2, W1f, out);  // ceil(400000/192)
}